// Round 5
// baseline (847.867 us; speedup 1.0000x reference)
//
#include <hip/hip_runtime.h>
#include <hip/hip_bf16.h>

typedef unsigned short bf16_t;
typedef __bf16 bf16x8 __attribute__((ext_vector_type(8)));
typedef float f32x4 __attribute__((ext_vector_type(4)));
typedef unsigned short ushort8_t __attribute__((ext_vector_type(8)));

__device__ __forceinline__ unsigned short f2bf(float x){
  union { __hip_bfloat16 h; unsigned short u; } c;
  c.h = __float2bfloat16(x);
  return c.u;
}
__device__ __forceinline__ float bf2f(bf16_t u){
  union { unsigned short u; __hip_bfloat16 h; } c;
  c.u = u;
  return __bfloat162float(c.h);
}
__device__ __forceinline__ ushort8_t cvt8(float4 a, float4 b){
  ushort8_t r;
  r[0]=f2bf(a.x); r[1]=f2bf(a.y); r[2]=f2bf(a.z); r[3]=f2bf(a.w);
  r[4]=f2bf(b.x); r[5]=f2bf(b.y); r[6]=f2bf(b.z); r[7]=f2bf(b.w);
  return r;
}

// Packed tile format: tile = 128 rows x 32 k bf16 = 8KB = exact LDS image:
// elem = r*32 + cs*8 + (k&7), cs = ((k>>3)&3) ^ ((r>>1)&3).
// Matrix = tiles[rowTile*KT + kTile].
__device__ __forceinline__ size_t pidx(int m, int k, int KT){
  const int r = m & 127, c = (k >> 3) & 3;
  const int cs = c ^ ((r >> 1) & 3);
  return ((size_t)((m >> 7)*KT + (k >> 5)))*4096 + r*32 + cs*8 + (k & 7);
}

// ---------------------------------------------------------------------------
// 256x128 (MxN) bf16 MFMA GEMM, BK=32, 8 waves (4Mx2N), reg-staged pipeline:
// global->VGPR (issued 2 tiles early) -> ds_write (1 tile early) -> ds_read.
// Raw s_barrier + lgkmcnt(0) only; NO global_load_lds -> no vmcnt drains.
// blockIdx=(col,row,ksplit); id%8 = col%8 when gridDim.x%8==0 (XCD colocation).
// AF32: A read directly from f32 row-major [M][lda] (compress); else packed.
// Output: f32 partials at C + bks*csplit.
// ---------------------------------------------------------------------------
template<int AF32>
__global__ __launch_bounds__(512, 4)
void gemm256(const void* __restrict__ Aptr, int KTA /*or lda*/,
             const bf16_t* __restrict__ Bpk, int KTB,
             float* __restrict__ C, int ldc, size_t csplit,
             int M, int KchunkT)
{
  __shared__ __align__(16) bf16_t As[2][8192];   // 2 x 16KB (two 128-row images)
  __shared__ __align__(16) bf16_t Bs[2][4096];   // 2 x 8KB
  const int tid = threadIdx.x;
  const int w = tid >> 6, lane = tid & 63;
  const int wm = w >> 1, wn = w & 1;
  const int lr = lane & 15, kq = lane >> 4;
  const int bcol = blockIdx.x, brow = blockIdx.y, bks = blockIdx.z;
  const int gn0 = bcol*128;
  const int kt0 = bks*KchunkT, nt = KchunkT;

  const int ttid = tid & 255, tsub = tid >> 8;
  ushort8_t va0, va1, vb0;
  const bf16_t* Bg = Bpk + ((size_t)bcol*KTB + kt0)*4096 + tid*8;
  const bf16_t* Ag = nullptr;
  const float*  Af = nullptr;
  int c0 = 0;
  if (AF32) {
    const int r = ttid >> 1;
    const int grow = min(brow*256 + tsub*128 + r, M-1);
    c0 = ((ttid & 1) << 1) ^ ((r >> 1) & 3);
    Af = (const float*)Aptr + (size_t)grow*KTA + (size_t)kt0*32;
  } else {
    Ag = (const bf16_t*)Aptr + ((size_t)(2*brow + tsub)*KTA + kt0)*4096 + ttid*16;
  }
  bf16_t* Al = &As[0][0] + tsub*4096 + ttid*16;
  bf16_t* Bl = &Bs[0][0] + tid*8;

#define LDT(t) do { \
    if (AF32) { const float* ap = Af + (size_t)(t)*32; \
      float4 f0 = *(const float4*)(ap + c0*8); float4 f1 = *(const float4*)(ap + c0*8 + 4); \
      float4 f2 = *(const float4*)(ap + (c0^1)*8); float4 f3 = *(const float4*)(ap + (c0^1)*8 + 4); \
      va0 = cvt8(f0,f1); va1 = cvt8(f2,f3); \
      vb0 = *(const ushort8_t*)(Bg + (size_t)(t)*4096); \
    } else { \
      va0 = *(const ushort8_t*)(Ag + (size_t)(t)*4096); \
      va1 = *(const ushort8_t*)(Ag + (size_t)(t)*4096 + 8); \
      vb0 = *(const ushort8_t*)(Bg + (size_t)(t)*4096); } \
  } while(0)
#define WRT(b) do { \
    *(ushort8_t*)(Al + (b)*8192) = va0; \
    *(ushort8_t*)(Al + (b)*8192 + 8) = va1; \
    *(ushort8_t*)(Bl + (b)*4096) = vb0; } while(0)

  LDT(0); WRT(0);
  if (nt > 1) LDT(1);
  asm volatile("s_waitcnt lgkmcnt(0)" ::: "memory");
  __builtin_amdgcn_s_barrier();
  __builtin_amdgcn_sched_barrier(0);

  const int kqs = kq ^ ((lr >> 1) & 3);
  const int abase = (wm >> 1)*4096 + ((wm & 1)*64 + lr)*32 + kqs*8;
  const int bbase = (wn*64 + lr)*32 + kqs*8;
  f32x4 acc[4][4] = {};

  for (int t = 0; t < nt; ++t) {
    const int cb = t & 1;
    const bf16_t* Ab = &As[0][0] + cb*8192 + abase;
    const bf16_t* Bb = &Bs[0][0] + cb*4096 + bbase;
    bf16x8 af[4], bfr[4];
#pragma unroll
    for (int mi = 0; mi < 4; mi++) af[mi]  = *(const bf16x8*)(Ab + mi*512);
#pragma unroll
    for (int ni = 0; ni < 4; ni++) bfr[ni] = *(const bf16x8*)(Bb + ni*512);
    if (t + 1 < nt) WRT(cb ^ 1);     // tile t+1 (regs loaded last step)
    if (t + 2 < nt) LDT(t + 2);      // issue loads for t+2
    __builtin_amdgcn_s_setprio(1);
#pragma unroll
    for (int mi = 0; mi < 4; mi++)
#pragma unroll
      for (int ni = 0; ni < 4; ni++)
        acc[mi][ni] = __builtin_amdgcn_mfma_f32_16x16x32_bf16(af[mi], bfr[ni], acc[mi][ni], 0, 0, 0);
    __builtin_amdgcn_s_setprio(0);
    asm volatile("s_waitcnt lgkmcnt(0)" ::: "memory");
    __builtin_amdgcn_s_barrier();
    __builtin_amdgcn_sched_barrier(0);
  }
#undef LDT
#undef WRT

  // epilogue: D row = kq*4 + i within 16x16 frag, col = lane&15
#pragma unroll
  for (int mi = 0; mi < 4; mi++) {
#pragma unroll
    for (int ni = 0; ni < 4; ni++) {
      const int col = gn0 + wn*64 + ni*16 + lr;
#pragma unroll
      for (int i = 0; i < 4; i++) {
        const int row = brow*256 + wm*64 + mi*16 + kq*4 + i;
        if (row < M)
          C[(size_t)bks*csplit + (size_t)row*ldc + col] = acc[mi][ni][i];
      }
    }
  }
}

// pack B (transpose): src [K][srcldN] f32; panel n-tile (n0t+bx), k-tile by.
__global__ void pack_b(const float* __restrict__ src, bf16_t* __restrict__ dst,
                       int srcldN, int KT, int n0t)
{
  const int ntb = blockIdx.x, kt = blockIdx.y;
  __shared__ float s[32][132];
  for (int i = threadIdx.x; i < 4096; i += 256) {
    const int kl = i >> 7, nl = i & 127;
    s[kl][nl] = src[(size_t)(kt*32 + kl)*srcldN + ntb*128 + nl];
  }
  __syncthreads();
  bf16_t* dt = dst + ((size_t)(n0t + ntb)*KT + kt)*4096;
  for (int u = threadIdx.x; u < 512; u += 256) {
    const int r = u >> 2, c = u & 3;
    const int cs = c ^ ((r >> 1) & 3);
    *(ushort4*)(dt + r*32 + cs*8) =
      make_ushort4(f2bf(s[c*8+0][r]), f2bf(s[c*8+1][r]), f2bf(s[c*8+2][r]), f2bf(s[c*8+3][r]));
    *(ushort4*)(dt + r*32 + cs*8 + 4) =
      make_ushort4(f2bf(s[c*8+4][r]), f2bf(s[c*8+5][r]), f2bf(s[c*8+6][r]), f2bf(s[c*8+7][r]));
  }
}

// sum 16 split-K partials + bias -> prop f32 + packed X right half
__global__ void reduce_compress(const float* __restrict__ part, const float* __restrict__ bias,
                                float* __restrict__ prop, bf16_t* __restrict__ Xp)
{
  const int idx = blockIdx.x*256 + threadIdx.x;   // < 921600
  const int m = idx >> 10, d = idx & 1023;
  float v = bias[d];
#pragma unroll
  for (int z = 0; z < 16; z++) v += part[(size_t)z*921600 + idx];
  prop[idx] = v;
  Xp[pidx(m, 1024 + d, 64)] = f2bf(v);
}

// merged reduce: sum 16 partials + Sum_e rowsum[b,e,i]*b_edge[e][d]
// -> packed X left AND Xh left (bf16)
__global__ void reduce_merged(const float* __restrict__ part, const float* __restrict__ rowsumS,
                              const float* __restrict__ be,
                              bf16_t* __restrict__ Xp, bf16_t* __restrict__ Xhp)
{
  const int idx = blockIdx.x*256 + threadIdx.x;   // < 921600
  const int m = idx >> 10, d = idx & 1023;
  const int b = m/15, i = m - b*15;
  float v = 0.f;
#pragma unroll
  for (int z = 0; z < 16; z++) v += part[(size_t)z*921600 + idx];
#pragma unroll
  for (int e = 0; e < 7; e++)
    v += rowsumS[(b*7 + e)*15 + i] * be[e*1024 + d];
  const bf16_t o = f2bf(v);
  Xp [pidx(m, d, 64)] = o;
  Xhp[pidx(m, d, 64)] = o;
}

// RZ reduce (4 partials): v=sigmoid(sum+bias); c<1024 (r): Xh right=bf16(r*prop);
// c>=1024 (z): Zbuf.
__global__ void reduce_rz(const float* __restrict__ part, const float* __restrict__ bias,
                          const float* __restrict__ prop, float* __restrict__ Zbuf,
                          bf16_t* __restrict__ Xhp)
{
  const int idx = blockIdx.x*256 + threadIdx.x;   // < 1843200
  const int m = idx >> 11, c = idx & 2047;
  float v = bias[c];
#pragma unroll
  for (int z = 0; z < 4; z++) v += part[(size_t)z*1843200 + idx];
  v = 1.f / (1.f + __expf(-v));
  if (c < 1024) Xhp[pidx(m, 1024 + c, 64)] = f2bf(v * prop[(size_t)m*1024 + c]);
  else          Zbuf[(size_t)m*1024 + (c - 1024)] = v;
}

// h reduce (8 partials): h=tanh(sum+bh); prop=(1-z)prop+z*h -> prop + X right
__global__ void reduce_h(const float* __restrict__ part, const float* __restrict__ bias,
                         const float* __restrict__ Zbuf, float* __restrict__ prop,
                         bf16_t* __restrict__ Xp)
{
  const int idx = blockIdx.x*256 + threadIdx.x;   // < 921600
  const int m = idx >> 10, d = idx & 1023;
  float v = bias[d];
#pragma unroll
  for (int z = 0; z < 8; z++) v += part[(size_t)z*921600 + idx];
  v = tanhf(v);
  const float zz = Zbuf[idx];
  const float pn = (1.f - zz)*prop[idx] + zz*v;
  prop[idx] = pn;
  Xp[pidx(m, 1024 + d, 64)] = f2bf(pn);
}

// u_row[e][h] = sum_d W_edge[e][h][d]*W_att[e][d]; u_col with W_att[e][1024+d]
__global__ void compute_u(const float* __restrict__ We, const float* __restrict__ Wa,
                          float* __restrict__ u_row, float* __restrict__ u_col)
{
  const int w = threadIdx.x >> 6, lane = threadIdx.x & 63;
  const int idx = blockIdx.x*4 + w;               // grid=1792 -> idx<7168
  const int e = idx >> 10, h = idx & 1023;
  const float* wep = We + ((size_t)e*1024 + h)*1024;
  const float* wr  = Wa + (size_t)e*2048;
  const float* wc  = wr + 1024;
  float ar = 0.f, ac = 0.f;
#pragma unroll
  for (int t = 0; t < 16; t++) {
    const float v = wep[lane + 64*t];
    ar += v*wr[lane + 64*t];
    ac += v*wc[lane + 64*t];
  }
  for (int off = 32; off; off >>= 1) { ar += __shfl_down(ar, off); ac += __shfl_down(ac, off); }
  if (lane == 0) { u_row[idx] = ar; u_col[idx] = ac; }
}

// crc[e] = b_edge[e].Wa_row[e], crc[7+e] = b_edge[e].Wa_col[e]
__global__ void crc_kernel(const float* __restrict__ be, const float* __restrict__ Wa,
                           float* __restrict__ crc)
{
  const int w = threadIdx.x >> 6, lane = threadIdx.x & 63;
  for (int idx = w; idx < 14; idx += 4) {
    const int e = idx >> 1, which = idx & 1;
    const float* bp = be + e*1024;
    const float* wp = Wa + (size_t)e*2048 + which*1024;
    float a = 0.f;
#pragma unroll
    for (int t = 0; t < 16; t++) a += bp[lane + 64*t]*wp[lane + 64*t];
    for (int off = 32; off; off >>= 1) a += __shfl_down(a, off);
    if (lane == 0) crc[which*7 + e] = a;
  }
}

// scores + per-(e,i) row sums
__global__ void attn_kernel(const float* __restrict__ prop, const float* __restrict__ u_row,
                            const float* __restrict__ u_col, const float* __restrict__ crc,
                            const float* __restrict__ b_att, float* __restrict__ scores,
                            float* __restrict__ rowsumS)
{
  const int b = blockIdx.x, e = blockIdx.y;
  __shared__ float rowv[15], colv[15], sc_s[225];
  const int w = threadIdx.x >> 6, lane = threadIdx.x & 63;
  const float* ur = u_row + (size_t)e*1024;
  const float* uc = u_col + (size_t)e*1024;
  for (int n = w; n < 15; n += 4) {
    const float* pr = prop + (size_t)(b*15 + n)*1024;
    float ar = 0.f, ac = 0.f;
#pragma unroll
    for (int t = 0; t < 16; t++) {
      const float pv = pr[lane + 64*t];
      ar += pv*ur[lane + 64*t];
      ac += pv*uc[lane + 64*t];
    }
    for (int off = 32; off; off >>= 1) { ar += __shfl_down(ar, off); ac += __shfl_down(ac, off); }
    if (lane == 0) { rowv[n] = ar; colv[n] = ac; }
  }
  __syncthreads();
  const float base = b_att[e] + crc[e] + crc[7 + e];
  for (int idx = threadIdx.x; idx < 225; idx += 256) {
    const int i = idx/15, j = idx - i*15;
    const float s = 1.f / (1.f + __expf(-(rowv[i] + colv[j] + base)));
    scores[((size_t)(b*7 + e)*15 + i)*15 + j] = s;
    sc_s[idx] = s;
  }
  __syncthreads();
  if (threadIdx.x < 15) {
    float rs = 0.f;
#pragma unroll
    for (int j = 0; j < 15; j++) rs += sc_s[threadIdx.x*15 + j];
    rowsumS[(b*7 + e)*15 + threadIdx.x] = rs;
  }
}

// Q[b,i,e*1024+d] = sum_j S[b,e,i,j]*prop[b,j,d]  -> packed A-format (KT=224)
__global__ __launch_bounds__(512)
void qmix_kernel(const float* __restrict__ prop, const float* __restrict__ scores,
                 bf16_t* __restrict__ Qp)
{
  const int b = blockIdx.x;
  __shared__ bf16_t ps[15*1024];
  __shared__ float ss[1575];
  const int tid = threadIdx.x;
  for (int idx = tid; idx < 15360; idx += 512)
    ps[idx] = f2bf(prop[(size_t)b*15360 + idx]);
  for (int idx = tid; idx < 1575; idx += 512)
    ss[idx] = scores[(size_t)b*1575 + idx];
  __syncthreads();
  float pv0[15], pv1[15];
#pragma unroll
  for (int j = 0; j < 15; j++) {
    pv0[j] = bf2f(ps[j*1024 + tid]);
    pv1[j] = bf2f(ps[j*1024 + tid + 512]);
  }
  for (int e = 0; e < 7; e++)
    for (int i = 0; i < 15; i++) {
      const float* se = ss + (e*15 + i)*15;
      float a0 = 0.f, a1 = 0.f;
#pragma unroll
      for (int j = 0; j < 15; j++) { a0 += se[j]*pv0[j]; a1 += se[j]*pv1[j]; }
      const int m = b*15 + i;
      Qp[pidx(m, e*1024 + tid,       224)] = f2bf(a0);
      Qp[pidx(m, e*1024 + tid + 512, 224)] = f2bf(a1);
    }
}

__global__ void cat2_kernel(const float* __restrict__ a, const float* __restrict__ b,
                            float* __restrict__ o)
{
  const int i = blockIdx.x*256 + threadIdx.x;
  if (i < 1024) o[i] = a[i];
  else if (i < 2048) o[i] = b[i - 1024];
}

// final outputs from last-iteration scores
__global__ void finalize_kernel(const float* __restrict__ scores, float* __restrict__ out)
{
  const int b = blockIdx.x;   // 0..59
  __shared__ float sc[1575];
  __shared__ float act[105];
  __shared__ float asum[15];
  __shared__ float t2[7];
  for (int idx = threadIdx.x; idx < 1575; idx += 256)
    sc[idx] = scores[(size_t)b*1575 + idx];
  __syncthreads();
  for (int idx = threadIdx.x; idx < 105; idx += 256) {
    const int i = idx/7, e = idx - i*7;
    float a = 0.f;
#pragma unroll
    for (int j = 0; j < 15; j++)
      a += (1.f - sc[i*15 + j]) * sc[(e*15 + i)*15 + j];
    act[idx] = a;
    out[(size_t)b*105 + idx] = a;
  }
  for (int idx = threadIdx.x; idx < 225; idx += 256) {
    const int i = idx/15, j = idx - i*15;
    out[6660 + (size_t)b*225 + idx] = 1.f - sc[i*15 + j];
  }
  if (threadIdx.x < 15) {
    const int i = threadIdx.x;
    float s = 0.f;
#pragma unroll
    for (int j = 0; j < 15; j++) s += 1.f - sc[i*15 + j];
    asum[i] = s;
  }
  __syncthreads();
  if (threadIdx.x < 7) {
    const int e = threadIdx.x;
    float t = 0.f;
#pragma unroll
    for (int i = 0; i < 15; i++) t += act[i*7 + e]*asum[i];
    t2[e] = t;
  }
  __syncthreads();
  if (threadIdx.x == 0) {
    float mx = -1e30f;
    for (int e = 1; e < 7; e++) mx = fmaxf(mx, t2[e]);
    float s = 0.f, ex[6];
    for (int e = 1; e < 7; e++) { ex[e-1] = __expf(t2[e] - mx); s += ex[e-1]; }
    for (int e = 1; e < 7; e++) out[6300 + (size_t)b*6 + (e-1)] = ex[e-1]/s;
  }
}

extern "C" void kernel_launch(void* const* d_in, const int* in_sizes, int n_in,
                              void* d_out, int out_size, void* d_ws, size_t ws_size,
                              hipStream_t stream)
{
  const float* pose = (const float*)d_in[0];
  const float* Wc   = (const float*)d_in[1];
  const float* bc   = (const float*)d_in[2];
  const float* We   = (const float*)d_in[3];
  const float* be   = (const float*)d_in[4];
  const float* Wa   = (const float*)d_in[5];
  const float* ba   = (const float*)d_in[6];
  const float* Wr   = (const float*)d_in[7];
  const float* br   = (const float*)d_in[8];
  const float* Wz   = (const float*)d_in[9];
  const float* bz   = (const float*)d_in[10];
  const float* Wh   = (const float*)d_in[11];
  const float* bh   = (const float*)d_in[12];
  float* out = (float*)d_out;

  // ---- workspace carving ----
  char* p = (char*)d_ws;
  auto alloc = [&](size_t b) { char* r = p; p += (b + 255) & ~(size_t)255; return r; };
  bf16_t* Wstackp = (bf16_t*)alloc(8ull*224*8192);   // 14.7 MB [8 nt][224 kt]
  bf16_t* Wrzp    = (bf16_t*)alloc(16ull*64*8192);   //  8.4 MB [16 nt][64 kt]
  bf16_t* Whp     = (bf16_t*)alloc(8ull*64*8192);    //  4.2 MB
  bf16_t* Xp      = (bf16_t*)alloc(8ull*64*8192);    //  4.2 MB [merged|prop]
  bf16_t* Xhp     = (bf16_t*)alloc(8ull*64*8192);    //  4.2 MB [merged|r*prop]
  float*  prop    = (float*) alloc(900ull*1024*4);   //  3.7 MB f32 state
  float*  scores  = (float*) alloc(60ull*1575*4);
  float*  rowsumS = (float*) alloc(60ull*105*4);
  float*  u_row   = (float*) alloc(7168*4);
  float*  u_col   = (float*) alloc(7168*4);
  float*  crc     = (float*) alloc(64);
  float*  brzv    = (float*) alloc(2048*4);
  // phase-union region (134.4 MB):
  // phase1: Wcp 52.4 @0 | partbuf 59 @52.4M
  // phase2: Qp 14.7 @0 | Zbuf 3.7 @14.7M | partbuf 59 @52.4M
  char* r1 = alloc(134400000ull);
  bf16_t* Wcp     = (bf16_t*)r1;                     // [8 nt][800 kt]
  bf16_t* Qp      = (bf16_t*)r1;                     // [8 rt][224 kt]
  float*  Zbuf    = (float*) (r1 + 14680064ull);
  float*  partbuf = (float*) (r1 + 52428800ull);     // up to 16 x 900x1024 f32

  // ---- precompute ----
  compute_u<<<1792, 256, 0, stream>>>(We, Wa, u_row, u_col);
  crc_kernel<<<1, 256, 0, stream>>>(be, Wa, crc);
  cat2_kernel<<<8, 256, 0, stream>>>(br, bz, brzv);
  pack_b<<<dim3(8,800), 256, 0, stream>>>(Wc, Wcp, 1024, 800, 0);
  pack_b<<<dim3(8,224), 256, 0, stream>>>(We, Wstackp, 1024, 224, 0);  // [7168][1024]
  pack_b<<<dim3(8,64),  256, 0, stream>>>(Wr, Wrzp, 1024, 64, 0);
  pack_b<<<dim3(8,64),  256, 0, stream>>>(Wz, Wrzp, 1024, 64, 8);
  pack_b<<<dim3(8,64),  256, 0, stream>>>(Wh, Whp, 1024, 64, 0);

  // compress: prop = pose @ W_compress + b_compress (A from f32, split-K=16)
  gemm256<1><<<dim3(8,4,16), 512, 0, stream>>>(pose, 25600, Wcp, 800,
      partbuf, 1024, 921600ull, 900, 50);
  reduce_compress<<<3600, 256, 0, stream>>>(partbuf, bc, prop, Xp);

  // ---- 6 recurrent iterations (last one: scores only) ----
  for (int it = 0; it < 6; it++) {
    attn_kernel<<<dim3(60,7), 256, 0, stream>>>(prop, u_row, u_col, crc, ba,
                                                scores, rowsumS);
    if (it == 5) break;
    // Q = S-mix of prop (packed); merged = Q @ Wstack (split-K=16)
    qmix_kernel<<<60, 512, 0, stream>>>(prop, scores, Qp);
    gemm256<0><<<dim3(8,4,16), 512, 0, stream>>>(Qp, 224, Wstackp, 224,
        partbuf, 1024, 921600ull, 900, 14);
    reduce_merged<<<3600, 256, 0, stream>>>(partbuf, rowsumS, be, Xp, Xhp);
    // [r|z] = X @ [Wr|Wz] (split-K=4)
    gemm256<0><<<dim3(16,4,4), 512, 0, stream>>>(Xp, 64, Wrzp, 64,
        partbuf, 2048, 1843200ull, 900, 16);
    reduce_rz<<<7200, 256, 0, stream>>>(partbuf, brzv, prop, Zbuf, Xhp);
    // h = Xh @ Wh (split-K=8)
    gemm256<0><<<dim3(8,4,8), 512, 0, stream>>>(Xhp, 64, Whp, 64,
        partbuf, 1024, 921600ull, 900, 8);
    reduce_h<<<3600, 256, 0, stream>>>(partbuf, bh, Zbuf, prop, Xp);
  }

  finalize_kernel<<<60, 256, 0, stream>>>(scores, out);
}

// Round 6
// 778.920 us; speedup vs baseline: 1.0885x; 1.0885x over previous
//
#include <hip/hip_runtime.h>
#include <hip/hip_bf16.h>

typedef unsigned short bf16_t;
typedef __bf16 bf16x8 __attribute__((ext_vector_type(8)));
typedef float f32x4 __attribute__((ext_vector_type(4)));
typedef unsigned short ushort8_t __attribute__((ext_vector_type(8)));

__device__ __forceinline__ unsigned short f2bf(float x){
  union { __hip_bfloat16 h; unsigned short u; } c;
  c.h = __float2bfloat16(x);
  return c.u;
}
__device__ __forceinline__ float bf2f(bf16_t u){
  union { unsigned short u; __hip_bfloat16 h; } c;
  c.u = u;
  return __bfloat162float(c.h);
}
__device__ __forceinline__ ushort8_t cvt8(float4 a, float4 b){
  ushort8_t r;
  r[0]=f2bf(a.x); r[1]=f2bf(a.y); r[2]=f2bf(a.z); r[3]=f2bf(a.w);
  r[4]=f2bf(b.x); r[5]=f2bf(b.y); r[6]=f2bf(b.z); r[7]=f2bf(b.w);
  return r;
}

// Packed tile format: tile = 128 rows x 32 k bf16 = 8KB = exact LDS image:
// elem = r*32 + cs*8 + (k&7), cs = ((k>>3)&3) ^ ((r>>1)&3).
// Matrix = tiles[rowTile*KT + kTile].
__device__ __forceinline__ size_t pidx(int m, int k, int KT){
  const int r = m & 127, c = (k >> 3) & 3;
  const int cs = c ^ ((r >> 1) & 3);
  return ((size_t)((m >> 7)*KT + (k >> 5)))*4096 + r*32 + cs*8 + (k & 7);
}

// ---------------------------------------------------------------------------
// 256x128 (MxN) bf16 MFMA GEMM, BK=32, 8 waves (4Mx2N), reg-staged pipeline:
// global->VGPR (2 tiles early) -> ds_write (1 tile early) -> ds_read.
// Staging is conflict-free: every ds_write is 16B at lane*16 stride.
// MODE 0: blockIdx=(col,row,ks)   -> id%8 = col%8   (B-sharers colocated)
// MODE 1: blockIdx=(ks,col,row)   -> id%8 = ks      (full per-XCD colocation)
// MODE 2: compress decode: x=slot(row,ks&1), y=col, z=ks>>1 -> id%8 = slot
//         (A f32-chunk sharers colocated, lockstep K streaming); A read
//         directly from f32 row-major [M][lda].
// Output: f32 partials at C + ks*csplit.
// ---------------------------------------------------------------------------
template<int MODE>
__global__ __launch_bounds__(512, 4)
void gemm256(const void* __restrict__ Aptr, int KTA /*or lda*/,
             const bf16_t* __restrict__ Bpk, int KTB,
             float* __restrict__ C, int ldc, size_t csplit,
             int M, int KchunkT)
{
  __shared__ __align__(16) bf16_t As[2][8192];   // 2 x 16KB (two 128-row images)
  __shared__ __align__(16) bf16_t Bs[2][4096];   // 2 x 8KB
  const int tid = threadIdx.x;
  const int w = tid >> 6, lane = tid & 63;
  const int wm = w >> 1, wn = w & 1;
  const int lr = lane & 15, kq = lane >> 4;
  int bcol, brow, bks;
  if (MODE == 0)      { bcol = blockIdx.x; brow = blockIdx.y; bks = blockIdx.z; }
  else if (MODE == 1) { bks = blockIdx.x;  bcol = blockIdx.y; brow = blockIdx.z; }
  else { brow = blockIdx.x & 3; bks = blockIdx.z*2 + (blockIdx.x >> 2); bcol = blockIdx.y; }
  const int gn0 = bcol*128;
  const int kt0 = bks*KchunkT, nt = KchunkT;

  // staging geometry (conflict-free): wave w owns A-image elems
  // [(w>>2)*4096 + (w&3)*1024 .. +1024) as va0/va1 (16B each at lane*16
  // stride), and B-image elems [w*512 .. +512) as vb0.
  const int aoff = (w & 3)*1024 + lane*8;        // within one 128-row image
  const int asub = w >> 2;                       // which image (row half)
  ushort8_t va0, va1, vb0;
  const bf16_t* Bg = Bpk + ((size_t)bcol*KTB + kt0)*4096 + w*512 + lane*8;
  const bf16_t* Ag = nullptr;
  const float *Af0 = nullptr, *Af1 = nullptr;
  if (MODE == 2) {
    const int r  = aoff >> 5;                    // row within image
    const int cs = (aoff >> 3) & 3;
    const int c  = cs ^ ((r >> 1) & 3);          // physical 8-k group
    const int g0 = min(brow*256 + asub*128 + r,      M-1);
    const int g1 = min(brow*256 + asub*128 + r + 16, M-1);
    Af0 = (const float*)Aptr + (size_t)g0*KTA + (size_t)kt0*32 + c*8;
    Af1 = (const float*)Aptr + (size_t)g1*KTA + (size_t)kt0*32 + c*8;
  } else {
    Ag = (const bf16_t*)Aptr + ((size_t)(2*brow + asub)*KTA + kt0)*4096 + aoff;
  }
  bf16_t* Al = &As[0][0] + asub*4096 + aoff;
  bf16_t* Bl = &Bs[0][0] + w*512 + lane*8;

#define LDT(t) do { \
    if (MODE == 2) { \
      const float* a0 = Af0 + (size_t)(t)*32; \
      const float* a1 = Af1 + (size_t)(t)*32; \
      va0 = cvt8(*(const float4*)a0, *(const float4*)(a0 + 4)); \
      va1 = cvt8(*(const float4*)a1, *(const float4*)(a1 + 4)); \
    } else { \
      va0 = *(const ushort8_t*)(Ag + (size_t)(t)*4096); \
      va1 = *(const ushort8_t*)(Ag + (size_t)(t)*4096 + 512); \
    } \
    vb0 = *(const ushort8_t*)(Bg + (size_t)(t)*4096); \
  } while(0)
#define WRT(b) do { \
    *(ushort8_t*)(Al + (b)*8192) = va0; \
    *(ushort8_t*)(Al + (b)*8192 + 512) = va1; \
    *(ushort8_t*)(Bl + (b)*4096) = vb0; } while(0)

  LDT(0); WRT(0);
  if (nt > 1) LDT(1);
  asm volatile("s_waitcnt lgkmcnt(0)" ::: "memory");
  __builtin_amdgcn_s_barrier();
  __builtin_amdgcn_sched_barrier(0);

  const int kqs = kq ^ ((lr >> 1) & 3);
  const int abase = (wm >> 1)*4096 + ((wm & 1)*64 + lr)*32 + kqs*8;
  const int bbase = (wn*64 + lr)*32 + kqs*8;
  f32x4 acc[4][4] = {};

  for (int t = 0; t < nt; ++t) {
    const int cb = t & 1;
    const bf16_t* Ab = &As[0][0] + cb*8192 + abase;
    const bf16_t* Bb = &Bs[0][0] + cb*4096 + bbase;
    bf16x8 af[4], bfr[4];
#pragma unroll
    for (int mi = 0; mi < 4; mi++) af[mi]  = *(const bf16x8*)(Ab + mi*512);
#pragma unroll
    for (int ni = 0; ni < 4; ni++) bfr[ni] = *(const bf16x8*)(Bb + ni*512);
    if (t + 1 < nt) WRT(cb ^ 1);     // tile t+1 (regs loaded last step)
    if (t + 2 < nt) LDT(t + 2);      // issue loads for t+2
    __builtin_amdgcn_s_setprio(1);
#pragma unroll
    for (int mi = 0; mi < 4; mi++)
#pragma unroll
      for (int ni = 0; ni < 4; ni++)
        acc[mi][ni] = __builtin_amdgcn_mfma_f32_16x16x32_bf16(af[mi], bfr[ni], acc[mi][ni], 0, 0, 0);
    __builtin_amdgcn_s_setprio(0);
    asm volatile("s_waitcnt lgkmcnt(0)" ::: "memory");
    __builtin_amdgcn_s_barrier();
    __builtin_amdgcn_sched_barrier(0);
  }
#undef LDT
#undef WRT

  // epilogue: D row = kq*4 + i within 16x16 frag, col = lane&15
#pragma unroll
  for (int mi = 0; mi < 4; mi++) {
#pragma unroll
    for (int ni = 0; ni < 4; ni++) {
      const int col = gn0 + wn*64 + ni*16 + lr;
#pragma unroll
      for (int i = 0; i < 4; i++) {
        const int row = brow*256 + wm*64 + mi*16 + kq*4 + i;
        if (row < M)
          C[(size_t)bks*csplit + (size_t)row*ldc + col] = acc[mi][ni][i];
      }
    }
  }
}

// pack B (transpose): src [K][srcldN] f32; panel n-tile (n0t+bx), k-tile by.
__global__ void pack_b(const float* __restrict__ src, bf16_t* __restrict__ dst,
                       int srcldN, int KT, int n0t)
{
  const int ntb = blockIdx.x, kt = blockIdx.y;
  __shared__ float s[32][132];
  for (int i = threadIdx.x; i < 4096; i += 256) {
    const int kl = i >> 7, nl = i & 127;
    s[kl][nl] = src[(size_t)(kt*32 + kl)*srcldN + ntb*128 + nl];
  }
  __syncthreads();
  bf16_t* dt = dst + ((size_t)(n0t + ntb)*KT + kt)*4096;
  for (int u = threadIdx.x; u < 512; u += 256) {
    const int r = u >> 2, c = u & 3;
    const int cs = c ^ ((r >> 1) & 3);
    *(ushort4*)(dt + r*32 + cs*8) =
      make_ushort4(f2bf(s[c*8+0][r]), f2bf(s[c*8+1][r]), f2bf(s[c*8+2][r]), f2bf(s[c*8+3][r]));
    *(ushort4*)(dt + r*32 + cs*8 + 4) =
      make_ushort4(f2bf(s[c*8+4][r]), f2bf(s[c*8+5][r]), f2bf(s[c*8+6][r]), f2bf(s[c*8+7][r]));
  }
}

// sum 8 split-K partials + bias -> prop f32 + packed X right half
__global__ void reduce_compress(const float* __restrict__ part, const float* __restrict__ bias,
                                float* __restrict__ prop, bf16_t* __restrict__ Xp)
{
  const int idx = blockIdx.x*256 + threadIdx.x;   // < 921600
  const int m = idx >> 10, d = idx & 1023;
  float v = bias[d];
#pragma unroll
  for (int z = 0; z < 8; z++) v += part[(size_t)z*921600 + idx];
  prop[idx] = v;
  Xp[pidx(m, 1024 + d, 64)] = f2bf(v);
}

// merged reduce: sum 8 partials + Sum_e rowsum[b,e,i]*b_edge[e][d]
// -> packed X left AND Xh left (bf16)
__global__ void reduce_merged(const float* __restrict__ part, const float* __restrict__ rowsumS,
                              const float* __restrict__ be,
                              bf16_t* __restrict__ Xp, bf16_t* __restrict__ Xhp)
{
  const int idx = blockIdx.x*256 + threadIdx.x;   // < 921600
  const int m = idx >> 10, d = idx & 1023;
  const int b = m/15, i = m - b*15;
  float v = 0.f;
#pragma unroll
  for (int z = 0; z < 8; z++) v += part[(size_t)z*921600 + idx];
#pragma unroll
  for (int e = 0; e < 7; e++)
    v += rowsumS[(b*7 + e)*15 + i] * be[e*1024 + d];
  const bf16_t o = f2bf(v);
  Xp [pidx(m, d, 64)] = o;
  Xhp[pidx(m, d, 64)] = o;
}

// RZ reduce (4 partials): v=sigmoid(sum+bias); c<1024 (r): Xh right=bf16(r*prop);
// c>=1024 (z): Zbuf.
__global__ void reduce_rz(const float* __restrict__ part, const float* __restrict__ bias,
                          const float* __restrict__ prop, float* __restrict__ Zbuf,
                          bf16_t* __restrict__ Xhp)
{
  const int idx = blockIdx.x*256 + threadIdx.x;   // < 1843200
  const int m = idx >> 11, c = idx & 2047;
  float v = bias[c];
#pragma unroll
  for (int z = 0; z < 4; z++) v += part[(size_t)z*1843200 + idx];
  v = 1.f / (1.f + __expf(-v));
  if (c < 1024) Xhp[pidx(m, 1024 + c, 64)] = f2bf(v * prop[(size_t)m*1024 + c]);
  else          Zbuf[(size_t)m*1024 + (c - 1024)] = v;
}

// h reduce (4 partials): h=tanh(sum+bh); prop=(1-z)prop+z*h -> prop + X right
__global__ void reduce_h(const float* __restrict__ part, const float* __restrict__ bias,
                         const float* __restrict__ Zbuf, float* __restrict__ prop,
                         bf16_t* __restrict__ Xp)
{
  const int idx = blockIdx.x*256 + threadIdx.x;   // < 921600
  const int m = idx >> 10, d = idx & 1023;
  float v = bias[d];
#pragma unroll
  for (int z = 0; z < 4; z++) v += part[(size_t)z*921600 + idx];
  v = tanhf(v);
  const float zz = Zbuf[idx];
  const float pn = (1.f - zz)*prop[idx] + zz*v;
  prop[idx] = pn;
  Xp[pidx(m, 1024 + d, 64)] = f2bf(pn);
}

// u_row[e][h] = sum_d W_edge[e][h][d]*W_att[e][d]; u_col with W_att[e][1024+d]
__global__ void compute_u(const float* __restrict__ We, const float* __restrict__ Wa,
                          float* __restrict__ u_row, float* __restrict__ u_col)
{
  const int w = threadIdx.x >> 6, lane = threadIdx.x & 63;
  const int idx = blockIdx.x*4 + w;               // grid=1792 -> idx<7168
  const int e = idx >> 10, h = idx & 1023;
  const float* wep = We + ((size_t)e*1024 + h)*1024;
  const float* wr  = Wa + (size_t)e*2048;
  const float* wc  = wr + 1024;
  float ar = 0.f, ac = 0.f;
#pragma unroll
  for (int t = 0; t < 16; t++) {
    const float v = wep[lane + 64*t];
    ar += v*wr[lane + 64*t];
    ac += v*wc[lane + 64*t];
  }
  for (int off = 32; off; off >>= 1) { ar += __shfl_down(ar, off); ac += __shfl_down(ac, off); }
  if (lane == 0) { u_row[idx] = ar; u_col[idx] = ac; }
}

// crc[e] = b_edge[e].Wa_row[e], crc[7+e] = b_edge[e].Wa_col[e]
__global__ void crc_kernel(const float* __restrict__ be, const float* __restrict__ Wa,
                           float* __restrict__ crc)
{
  const int w = threadIdx.x >> 6, lane = threadIdx.x & 63;
  for (int idx = w; idx < 14; idx += 4) {
    const int e = idx >> 1, which = idx & 1;
    const float* bp = be + e*1024;
    const float* wp = Wa + (size_t)e*2048 + which*1024;
    float a = 0.f;
#pragma unroll
    for (int t = 0; t < 16; t++) a += bp[lane + 64*t]*wp[lane + 64*t];
    for (int off = 32; off; off >>= 1) a += __shfl_down(a, off);
    if (lane == 0) crc[which*7 + e] = a;
  }
}

// scores + per-(e,i) row sums
__global__ void attn_kernel(const float* __restrict__ prop, const float* __restrict__ u_row,
                            const float* __restrict__ u_col, const float* __restrict__ crc,
                            const float* __restrict__ b_att, float* __restrict__ scores,
                            float* __restrict__ rowsumS)
{
  const int b = blockIdx.x, e = blockIdx.y;
  __shared__ float rowv[15], colv[15], sc_s[225];
  const int w = threadIdx.x >> 6, lane = threadIdx.x & 63;
  const float* ur = u_row + (size_t)e*1024;
  const float* uc = u_col + (size_t)e*1024;
  for (int n = w; n < 15; n += 4) {
    const float* pr = prop + (size_t)(b*15 + n)*1024;
    float ar = 0.f, ac = 0.f;
#pragma unroll
    for (int t = 0; t < 16; t++) {
      const float pv = pr[lane + 64*t];
      ar += pv*ur[lane + 64*t];
      ac += pv*uc[lane + 64*t];
    }
    for (int off = 32; off; off >>= 1) { ar += __shfl_down(ar, off); ac += __shfl_down(ac, off); }
    if (lane == 0) { rowv[n] = ar; colv[n] = ac; }
  }
  __syncthreads();
  const float base = b_att[e] + crc[e] + crc[7 + e];
  for (int idx = threadIdx.x; idx < 225; idx += 256) {
    const int i = idx/15, j = idx - i*15;
    const float s = 1.f / (1.f + __expf(-(rowv[i] + colv[j] + base)));
    scores[((size_t)(b*7 + e)*15 + i)*15 + j] = s;
    sc_s[idx] = s;
  }
  __syncthreads();
  if (threadIdx.x < 15) {
    float rs = 0.f;
#pragma unroll
    for (int j = 0; j < 15; j++) rs += sc_s[threadIdx.x*15 + j];
    rowsumS[(b*7 + e)*15 + threadIdx.x] = rs;
  }
}

// Q[b,i,e*1024+d] = sum_j S[b,e,i,j]*prop[b,j,d] -> packed A-format (KT=224)
// grid (60, 2) x 512 threads; each thread owns one d column (register prop).
__global__ __launch_bounds__(512)
void qmix_kernel(const float* __restrict__ prop, const float* __restrict__ scores,
                 bf16_t* __restrict__ Qp)
{
  const int b = blockIdx.x;
  const int d = blockIdx.y*512 + threadIdx.x;
  __shared__ float ss[1575];
  for (int idx = threadIdx.x; idx < 1575; idx += 512)
    ss[idx] = scores[(size_t)b*1575 + idx];
  float pv[15];
#pragma unroll
  for (int j = 0; j < 15; j++)
    pv[j] = prop[(size_t)(b*15 + j)*1024 + d];
  __syncthreads();
  for (int e = 0; e < 7; e++)
#pragma unroll
    for (int i = 0; i < 15; i++) {
      const float* se = ss + (e*15 + i)*15;
      float a = 0.f;
#pragma unroll
      for (int j = 0; j < 15; j++) a += se[j]*pv[j];
      Qp[pidx(b*15 + i, e*1024 + d, 224)] = f2bf(a);
    }
}

__global__ void cat2_kernel(const float* __restrict__ a, const float* __restrict__ b,
                            float* __restrict__ o)
{
  const int i = blockIdx.x*256 + threadIdx.x;
  if (i < 1024) o[i] = a[i];
  else if (i < 2048) o[i] = b[i - 1024];
}

// final outputs from last-iteration scores
__global__ void finalize_kernel(const float* __restrict__ scores, float* __restrict__ out)
{
  const int b = blockIdx.x;   // 0..59
  __shared__ float sc[1575];
  __shared__ float act[105];
  __shared__ float asum[15];
  __shared__ float t2[7];
  for (int idx = threadIdx.x; idx < 1575; idx += 256)
    sc[idx] = scores[(size_t)b*1575 + idx];
  __syncthreads();
  for (int idx = threadIdx.x; idx < 105; idx += 256) {
    const int i = idx/7, e = idx - i*7;
    float a = 0.f;
#pragma unroll
    for (int j = 0; j < 15; j++)
      a += (1.f - sc[i*15 + j]) * sc[(e*15 + i)*15 + j];
    act[idx] = a;
    out[(size_t)b*105 + idx] = a;
  }
  for (int idx = threadIdx.x; idx < 225; idx += 256) {
    const int i = idx/15, j = idx - i*15;
    out[6660 + (size_t)b*225 + idx] = 1.f - sc[i*15 + j];
  }
  if (threadIdx.x < 15) {
    const int i = threadIdx.x;
    float s = 0.f;
#pragma unroll
    for (int j = 0; j < 15; j++) s += 1.f - sc[i*15 + j];
    asum[i] = s;
  }
  __syncthreads();
  if (threadIdx.x < 7) {
    const int e = threadIdx.x;
    float t = 0.f;
#pragma unroll
    for (int i = 0; i < 15; i++) t += act[i*7 + e]*asum[i];
    t2[e] = t;
  }
  __syncthreads();
  if (threadIdx.x == 0) {
    float mx = -1e30f;
    for (int e = 1; e < 7; e++) mx = fmaxf(mx, t2[e]);
    float s = 0.f, ex[6];
    for (int e = 1; e < 7; e++) { ex[e-1] = __expf(t2[e] - mx); s += ex[e-1]; }
    for (int e = 1; e < 7; e++) out[6300 + (size_t)b*6 + (e-1)] = ex[e-1]/s;
  }
}

extern "C" void kernel_launch(void* const* d_in, const int* in_sizes, int n_in,
                              void* d_out, int out_size, void* d_ws, size_t ws_size,
                              hipStream_t stream)
{
  const float* pose = (const float*)d_in[0];
  const float* Wc   = (const float*)d_in[1];
  const float* bc   = (const float*)d_in[2];
  const float* We   = (const float*)d_in[3];
  const float* be   = (const float*)d_in[4];
  const float* Wa   = (const float*)d_in[5];
  const float* ba   = (const float*)d_in[6];
  const float* Wr   = (const float*)d_in[7];
  const float* br   = (const float*)d_in[8];
  const float* Wz   = (const float*)d_in[9];
  const float* bz   = (const float*)d_in[10];
  const float* Wh   = (const float*)d_in[11];
  const float* bh   = (const float*)d_in[12];
  float* out = (float*)d_out;

  // ---- workspace carving ----
  char* p = (char*)d_ws;
  auto alloc = [&](size_t b) { char* r = p; p += (b + 255) & ~(size_t)255; return r; };
  bf16_t* Wstackp = (bf16_t*)alloc(8ull*224*8192);   // 14.7 MB [8 nt][224 kt]
  bf16_t* Wrzp    = (bf16_t*)alloc(16ull*64*8192);   //  8.4 MB [16 nt][64 kt]
  bf16_t* Whp     = (bf16_t*)alloc(8ull*64*8192);    //  4.2 MB
  bf16_t* Xp      = (bf16_t*)alloc(8ull*64*8192);    //  4.2 MB [merged|prop]
  bf16_t* Xhp     = (bf16_t*)alloc(8ull*64*8192);    //  4.2 MB [merged|r*prop]
  float*  prop    = (float*) alloc(900ull*1024*4);   //  3.7 MB f32 state
  float*  scores  = (float*) alloc(60ull*1575*4);
  float*  rowsumS = (float*) alloc(60ull*105*4);
  float*  u_row   = (float*) alloc(7168*4);
  float*  u_col   = (float*) alloc(7168*4);
  float*  crc     = (float*) alloc(64);
  float*  brzv    = (float*) alloc(2048*4);
  // phase-union region (134.4 MB):
  // phase1: Wcp 52.4 @0 | partbuf @52.4M (8 x 3.7 = 29.5)
  // phase2: Qp 14.7 @0 | Zbuf 3.7 @14.7M | partbuf @52.4M (max 4 x 7.4 = 29.5)
  char* r1 = alloc(134400000ull);
  bf16_t* Wcp     = (bf16_t*)r1;                     // [8 nt][800 kt]
  bf16_t* Qp      = (bf16_t*)r1;                     // [8 rt][224 kt]
  float*  Zbuf    = (float*) (r1 + 14680064ull);
  float*  partbuf = (float*) (r1 + 52428800ull);

  // ---- precompute ----
  compute_u<<<1792, 256, 0, stream>>>(We, Wa, u_row, u_col);
  crc_kernel<<<1, 256, 0, stream>>>(be, Wa, crc);
  cat2_kernel<<<8, 256, 0, stream>>>(br, bz, brzv);
  pack_b<<<dim3(8,800), 256, 0, stream>>>(Wc, Wcp, 1024, 800, 0);
  pack_b<<<dim3(8,224), 256, 0, stream>>>(We, Wstackp, 1024, 224, 0);
  pack_b<<<dim3(8,64),  256, 0, stream>>>(Wr, Wrzp, 1024, 64, 0);
  pack_b<<<dim3(8,64),  256, 0, stream>>>(Wz, Wrzp, 1024, 64, 8);
  pack_b<<<dim3(8,64),  256, 0, stream>>>(Wh, Whp, 1024, 64, 0);

  // compress: prop = pose @ W_compress + b_compress
  // MODE2: split-K=8, A-chunk sharers colocated per XCD
  gemm256<2><<<dim3(8,8,4), 512, 0, stream>>>(pose, 25600, Wcp, 800,
      partbuf, 1024, 921600ull, 900, 100);
  reduce_compress<<<3600, 256, 0, stream>>>(partbuf, bc, prop, Xp);

  // ---- 6 recurrent iterations (last one: scores only) ----
  for (int it = 0; it < 6; it++) {
    attn_kernel<<<dim3(60,7), 256, 0, stream>>>(prop, u_row, u_col, crc, ba,
                                                scores, rowsumS);
    if (it == 5) break;
    // Q = S-mix of prop (packed); merged = Q @ Wstack (MODE1, ks=8: full
    // per-XCD colocation, working set 3.4 MB < 4 MB L2)
    qmix_kernel<<<dim3(60,2), 512, 0, stream>>>(prop, scores, Qp);
    gemm256<1><<<dim3(8,8,4), 512, 0, stream>>>(Qp, 224, Wstackp, 224,
        partbuf, 1024, 921600ull, 900, 28);
    reduce_merged<<<3600, 256, 0, stream>>>(partbuf, rowsumS, be, Xp, Xhp);
    // [r|z] = X @ [Wr|Wz] (MODE0, split-K=4)
    gemm256<0><<<dim3(16,4,4), 512, 0, stream>>>(Xp, 64, Wrzp, 64,
        partbuf, 2048, 1843200ull, 900, 16);
    reduce_rz<<<7200, 256, 0, stream>>>(partbuf, brzv, prop, Zbuf, Xhp);
    // h = Xh @ Wh (MODE0, split-K=4)
    gemm256<0><<<dim3(8,4,4), 512, 0, stream>>>(Xhp, 64, Whp, 64,
        partbuf, 1024, 921600ull, 900, 16);
    reduce_h<<<3600, 256, 0, stream>>>(partbuf, bh, Zbuf, prop, Xp);
  }

  finalize_kernel<<<60, 256, 0, stream>>>(scores, out);
}